// Round 3
// baseline (77.986 us; speedup 1.0000x reference)
//
#include <hip/hip_runtime.h>
#include <cfloat>
#include <cmath>

// x[B,W,L], shapelets[N,L], cls_w[1,N], cls_b[1]
constexpr int B = 64;
constexpr int W = 256;
constexpr int N = 128;
constexpr int L = 64;
constexpr int NC = 32;        // window-chunks per batch element (R3: was 16)
constexpr int WPB = W / NC;   // 8 windows per block

// Arrival counters for the last-block-per-b head. Zero-initialized at module
// load (NOT in the poisoned workspace); last block restores 0 for the next
// graph replay. R2 verified this protocol passes under graph capture +
// rocprof counter replay.
__device__ int g_cnt[B];

// VALU-pipe cross-lane add (DPP), avoiding the DS pipe entirely.
// CTRL: 0xB1 = quad_perm xor1, 0x4E = quad_perm xor2,
//       0x141 = row_half_mirror (xor-4 class), 0x140 = row_mirror (xor-8).
template <int CTRL>
__device__ __forceinline__ float dpp_add(float v) {
  return v + __int_as_float(__builtin_amdgcn_update_dpp(
                 0, __float_as_int(v), CTRL, 0xF, 0xF, true));
}

// ---------------------------------------------------------------------------
// FUSED kernel, round 3. R2 post-mortem: sc1-store protocol correct; kernel
// inferred ~21us vs ~9us of issue work -> latency-bound at 4 blocks/CU
// (16/32 waves). This round: NC=32 -> 2048 blocks -> 8 blocks/CU = FULL
// 32-wave occupancy (VGPR 52 and LDS 2.3KB both permit it), and the
// 1024x-redundant per-block ||s||^2 DPP tree is deleted (tail recomputes it
// once per b, the proven original-k2 path).
//
// Hot loop per window is UNCHANGED (G=8 lane groups x 4 shapelets is the
// VALU/DS seesaw optimum: 56 VALU + 2 ds_read_b128 per wave per window,
// SQ_LDS_BANK_CONFLICT = 0).
// grid = B*NC = 2048, block = 256.
// ---------------------------------------------------------------------------
__global__ __launch_bounds__(256)
void shapelet_fused_kernel(const float* __restrict__ x,
                           const float* __restrict__ shp,
                           const float* __restrict__ cls_w,
                           const float* __restrict__ cls_b,
                           float* __restrict__ part,
                           float* __restrict__ out) {
  __shared__ float xs[WPB * L];   // 2 KB
  __shared__ float xnorm_s[WPB];
  __shared__ int s_last;
  __shared__ float red[2];

  const int b = blockIdx.x >> 5;   // NC = 32
  const int c = blockIdx.x & 31;
  const int tid = threadIdx.x;
  const int oct = tid & 7;        // eighth-of-row owned by this lane
  const int grp = tid >> 3;       // 0..31 -> shapelets 4*grp..4*grp+3
  const int n0 = grp * 4;

  // --- Stage x[b, c*8:(c+1)*8, :]: 128 float4 by threads 0..127 (waves 0-1
  // fully active, waves 2-3 skip — wave-uniform, no divergence). ||x_w||^2
  // via 16-lane DPP reduction, zero DS-pipe swizzles.
  if (tid < WPB * L / 4) {
    const float4* xg =
        (const float4*)(x + ((size_t)b * W + (size_t)c * WPB) * L);
    float4 v = xg[tid];
    ((float4*)xs)[tid] = v;
    float p = v.x * v.x + v.y * v.y + v.z * v.z + v.w * v.w;
    p = dpp_add<0xB1>(p);    // xor1 (quad)
    p = dpp_add<0x4E>(p);    // xor2 (quad)
    p = dpp_add<0x141>(p);   // 4<->8 within row of 16
    p = dpp_add<0x140>(p);   // mirror row of 16
    if ((tid & 15) == 0) xnorm_s[tid >> 4] = p;
  }

  // --- Eighth-rows of 4 shapelets: 8 NAMED float4 (32 VGPRs). No arrays,
  // no q-tree (R3: ||s||^2 moved to the tail, once per b).
  const float4* g0 = (const float4*)(shp + (size_t)(n0 + 0) * L + oct * 8);
  const float4* g1 = (const float4*)(shp + (size_t)(n0 + 1) * L + oct * 8);
  const float4* g2 = (const float4*)(shp + (size_t)(n0 + 2) * L + oct * 8);
  const float4* g3 = (const float4*)(shp + (size_t)(n0 + 3) * L + oct * 8);
  const float4 s0a = g0[0], s0b = g0[1];
  const float4 s1a = g1[0], s1b = g1[1];
  const float4 s2a = g2[0], s2b = g2[1];
  const float4 s3a = g3[0], s3b = g3[1];

  __syncthreads();

  // --- min over the 8 windows of (xnorm_w - 2*dot(x_w, s_n)).
  float best0 = FLT_MAX, best1 = FLT_MAX, best2 = FLT_MAX, best3 = FLT_MAX;
  for (int w = 0; w < WPB; ++w) {
    const float4* xr = (const float4*)(xs + (size_t)w * L + oct * 8);
    const float4 xa = xr[0];
    const float4 xb = xr[1];

    float d0 = xa.x * s0a.x + xa.y * s0a.y;
    float d1 = xa.x * s1a.x + xa.y * s1a.y;
    float d2 = xa.x * s2a.x + xa.y * s2a.y;
    float d3 = xa.x * s3a.x + xa.y * s3a.y;
    d0 = fmaf(xa.z, s0a.z, d0); d0 = fmaf(xa.w, s0a.w, d0);
    d1 = fmaf(xa.z, s1a.z, d1); d1 = fmaf(xa.w, s1a.w, d1);
    d2 = fmaf(xa.z, s2a.z, d2); d2 = fmaf(xa.w, s2a.w, d2);
    d3 = fmaf(xa.z, s3a.z, d3); d3 = fmaf(xa.w, s3a.w, d3);
    d0 = fmaf(xb.x, s0b.x, d0); d0 = fmaf(xb.y, s0b.y, d0);
    d1 = fmaf(xb.x, s1b.x, d1); d1 = fmaf(xb.y, s1b.y, d1);
    d2 = fmaf(xb.x, s2b.x, d2); d2 = fmaf(xb.y, s2b.y, d2);
    d3 = fmaf(xb.x, s3b.x, d3); d3 = fmaf(xb.y, s3b.y, d3);
    d0 = fmaf(xb.z, s0b.z, d0); d0 = fmaf(xb.w, s0b.w, d0);
    d1 = fmaf(xb.z, s1b.z, d1); d1 = fmaf(xb.w, s1b.w, d1);
    d2 = fmaf(xb.z, s2b.z, d2); d2 = fmaf(xb.w, s2b.w, d2);
    d3 = fmaf(xb.z, s3b.z, d3); d3 = fmaf(xb.w, s3b.w, d3);

    d0 = dpp_add<0xB1>(d0);  d1 = dpp_add<0xB1>(d1);
    d2 = dpp_add<0xB1>(d2);  d3 = dpp_add<0xB1>(d3);
    d0 = dpp_add<0x4E>(d0);  d1 = dpp_add<0x4E>(d1);
    d2 = dpp_add<0x4E>(d2);  d3 = dpp_add<0x4E>(d3);
    d0 = dpp_add<0x141>(d0); d1 = dpp_add<0x141>(d1);
    d2 = dpp_add<0x141>(d2); d3 = dpp_add<0x141>(d3);

    const float xn = xnorm_s[w];
    best0 = fminf(best0, fmaf(-2.f, d0, xn));
    best1 = fminf(best1, fmaf(-2.f, d1, xn));
    best2 = fminf(best2, fmaf(-2.f, d2, xn));
    best3 = fminf(best3, fmaf(-2.f, d3, xn));
  }

  // --- oct-leader writes 4 chunk-mins (xnorm - 2dot only; ||s||^2 added in
  // tail) as AGENT-scope (sc1) write-through stores: cross-XCD visible with
  // no cache-maintenance instructions (R2-verified protocol).
  if (oct == 0) {
    float* p = part + ((size_t)b * NC + c) * N + n0;
    __hip_atomic_store(p + 0, best0, __ATOMIC_RELAXED,
                       __HIP_MEMORY_SCOPE_AGENT);
    __hip_atomic_store(p + 1, best1, __ATOMIC_RELAXED,
                       __HIP_MEMORY_SCOPE_AGENT);
    __hip_atomic_store(p + 2, best2, __ATOMIC_RELAXED,
                       __HIP_MEMORY_SCOPE_AGENT);
    __hip_atomic_store(p + 3, best3, __ATOMIC_RELAXED,
                       __HIP_MEMORY_SCOPE_AGENT);
  }

  // --- Arrival. __syncthreads() emits s_waitcnt vmcnt(0) in every wave, so
  // all sc1 part-stores are at the agent-coherent point before tid0's
  // relaxed agent arrival add.
  __syncthreads();
  if (tid == 0) {
    int done = __hip_atomic_fetch_add(&g_cnt[b], 1, __ATOMIC_RELAXED,
                                      __HIP_MEMORY_SCOPE_AGENT);
    s_last = (done == NC - 1) ? 1 : 0;
    if (done == NC - 1)
      __hip_atomic_store(&g_cnt[b], 0, __ATOMIC_RELAXED,
                         __HIP_MEMORY_SCOPE_AGENT);  // clean for next replay
  }
  __syncthreads();
  if (!s_last) return;

  // --- Last block for this b: classifier head (original-k2 math: min over
  // chunks + ||s_n||^2 + sqrt + dot + sigmoid). All 256 threads alive, so
  // the barrier below is safe. part reads are agent-scope loads; for fixed
  // cc, 64 lanes read consecutive n -> per-instruction coalesced.
  float v = 0.f;
  if (tid < N) {
    const float* pb = part + (size_t)b * NC * N + tid;
    float m = FLT_MAX;
#pragma unroll
    for (int cc = 0; cc < NC; ++cc) {
      float pv = __hip_atomic_load(pb + cc * N, __ATOMIC_RELAXED,
                                   __HIP_MEMORY_SCOPE_AGENT);
      m = fminf(m, pv);
    }
    // ||s_n||^2 once per b (shp is L2-warm by now).
    float sn = 0.f;
    const float4* sg = (const float4*)(shp + (size_t)tid * L);
#pragma unroll
    for (int i = 0; i < L / 4; ++i) {
      float4 s = sg[i];
      sn = fmaf(s.x, s.x, sn);
      sn = fmaf(s.y, s.y, sn);
      sn = fmaf(s.z, s.z, sn);
      sn = fmaf(s.w, s.w, sn);
    }
    float d2 = fmaxf(m + sn, 0.f);  // guard fp rounding before sqrt
    v = sqrtf(d2) * cls_w[tid];
  }
#pragma unroll
  for (int off = 32; off > 0; off >>= 1) v += __shfl_down(v, off, 64);
  if ((tid & 63) == 0) red[tid >> 6] = v;
  __syncthreads();
  if (tid == 0) {
    float z = red[0] + red[1] + cls_b[0];
    out[b] = 1.0f / (1.0f + expf(-z));
  }
}

extern "C" void kernel_launch(void* const* d_in, const int* in_sizes, int n_in,
                              void* d_out, int out_size, void* d_ws,
                              size_t ws_size, hipStream_t stream) {
  const float* x = (const float*)d_in[0];      // [B, W, L]
  const float* shp = (const float*)d_in[1];    // [N, L]
  const float* cls_w = (const float*)d_in[2];  // [1, N]
  const float* cls_b = (const float*)d_in[3];  // [1]
  float* out = (float*)d_out;                  // [B, 1]
  float* part = (float*)d_ws;                  // [B, NC, N] fp32 (1 MB)

  shapelet_fused_kernel<<<B * NC, 256, 0, stream>>>(x, shp, cls_w, cls_b,
                                                    part, out);
}